// Round 7
// baseline (26042.273 us; speedup 1.0000x reference)
//
#include <hip/hip_runtime.h>
#include <stdint.h>

#define T_STEPS 8192
#define IN_DIM  512
#define HID     1024
#define G4      4096
#define NBLK    64          // recurrent blocks (1 per CU, all co-resident)
#define NW      16          // waves per block

typedef unsigned long long u64;

// ---------------------------------------------------------------------------
// Kernel 1: x_gates[t][r] = sum_k input[t][k] * W_ih[r][k] + b_ih[r] + b_hh[r]
// fp32 tiled GEMM (NT), 128x128 tile, K-tile 8, 256 threads, 8x8 per thread.
// ---------------------------------------------------------------------------
__global__ __launch_bounds__(256) void gemm_xgates(
    const float* __restrict__ A,    // [8192][512]
    const float* __restrict__ W,    // [4096][512]
    const float* __restrict__ bih,  // [4096]
    const float* __restrict__ bhh,  // [4096]
    float* __restrict__ xg)         // [8192][4096]
{
    __shared__ float At[8][128];   // k-major A tile
    __shared__ float Bt[8][128];   // k-major W tile
    const int tid = threadIdx.x;
    const int r0 = blockIdx.x * 128;   // gate-row dim (4096)
    const int t0 = blockIdx.y * 128;   // time dim (8192)
    const int tx = tid & 15, ty = tid >> 4;
    const int lrow = tid >> 1;         // 0..127
    const int kq   = (tid & 1) * 4;    // 0 or 4

    float acc[8][8];
#pragma unroll
    for (int i = 0; i < 8; ++i)
#pragma unroll
        for (int j = 0; j < 8; ++j) acc[i][j] = 0.f;

    for (int k0 = 0; k0 < IN_DIM; k0 += 8) {
        float4 av = *(const float4*)&A[(size_t)(t0 + lrow) * IN_DIM + k0 + kq];
        float4 bv = *(const float4*)&W[(size_t)(r0 + lrow) * IN_DIM + k0 + kq];
        __syncthreads();
        At[kq + 0][lrow] = av.x; At[kq + 1][lrow] = av.y;
        At[kq + 2][lrow] = av.z; At[kq + 3][lrow] = av.w;
        Bt[kq + 0][lrow] = bv.x; Bt[kq + 1][lrow] = bv.y;
        Bt[kq + 2][lrow] = bv.z; Bt[kq + 3][lrow] = bv.w;
        __syncthreads();
#pragma unroll
        for (int k = 0; k < 8; ++k) {
            float4 a0 = *(const float4*)&At[k][ty * 8];
            float4 a1 = *(const float4*)&At[k][ty * 8 + 4];
            float4 b0 = *(const float4*)&Bt[k][tx * 8];
            float4 b1 = *(const float4*)&Bt[k][tx * 8 + 4];
            float aa[8] = {a0.x, a0.y, a0.z, a0.w, a1.x, a1.y, a1.z, a1.w};
            float bb[8] = {b0.x, b0.y, b0.z, b0.w, b1.x, b1.y, b1.z, b1.w};
#pragma unroll
            for (int i = 0; i < 8; ++i)
#pragma unroll
                for (int j = 0; j < 8; ++j) acc[i][j] += aa[i] * bb[j];
        }
    }

    float bias[8];
#pragma unroll
    for (int j = 0; j < 8; ++j) {
        int r = r0 + tx * 8 + j;
        bias[j] = bih[r] + bhh[r];
    }
#pragma unroll
    for (int i = 0; i < 8; ++i) {
        int t = t0 + ty * 8 + i;
        float4 o0 = make_float4(acc[i][0] + bias[0], acc[i][1] + bias[1],
                                acc[i][2] + bias[2], acc[i][3] + bias[3]);
        float4 o1 = make_float4(acc[i][4] + bias[4], acc[i][5] + bias[5],
                                acc[i][6] + bias[6], acc[i][7] + bias[7]);
        *(float4*)&xg[(size_t)t * G4 + r0 + tx * 8]     = o0;
        *(float4*)&xg[(size_t)t * G4 + r0 + tx * 8 + 4] = o1;
    }
}

// ---------------------------------------------------------------------------
// Kernel 2: persistent recurrent LSTM — minimal serial chain.
//
// 64 blocks x 1024 threads (16 waves, 1 block/CU). Wave w owns h[16b+w] and
// its 4 gate rows; W_hh slice pinned in registers (64 f32/lane).
//
// Per step, per wave:
//   poll   : lane l spins on hdata[par][64w + l] (ONE dwordx2/lane/iter)
//            until all 64 tags == t. Data IS the flag; no fences.
//   deposit: payload -> hinp[64w + l]   (stride-1, conflict-free)
//   barrier: single __syncthreads per step
//   compute: 64 fma vs register weights, 6-op DPP reduce (lane63 holds sums),
//            activations valid in lane 63 only (no readlane broadcast)
//   publish: lane 63 stores tagged u64 {t+1, h} + the hs epilogue copy.
//            No barrier B, no LDS funnel — h is visible ~1 wave-latency
//            after its dot finishes.
// Safety: parity double-buffer; any h_{t+2} write is transitively ordered
// after all reads of h_t (publication of h_{t+1} required consuming h_t).
// Own-store-ack folding into the next poll's vmcnt(0) is benign: h can't be
// observed anywhere before those stores reach the coherence point anyway.
// ---------------------------------------------------------------------------
__device__ __forceinline__ float sigm_f(float x) {
    return 1.f / (1.f + __expf(-x));
}
__device__ __forceinline__ float tanh_f(float x) {
    x = fminf(fmaxf(x, -15.f), 15.f);
    float e = __expf(2.f * x);
    return (e - 1.f) / (e + 1.f);
}

// Wave64 sum; result valid in lane 63 only. DPP ctrl: 0x110+N = row_shr:N,
// 0x142 = row_bcast:15, 0x143 = row_bcast:31. (R6-verified encodings.)
__device__ __forceinline__ float dpp_reduce_add(float x) {
    int v;
    v = __builtin_amdgcn_update_dpp(0, __float_as_int(x), 0x111, 0xf, 0xf, true);
    x += __int_as_float(v);
    v = __builtin_amdgcn_update_dpp(0, __float_as_int(x), 0x112, 0xf, 0xf, true);
    x += __int_as_float(v);
    v = __builtin_amdgcn_update_dpp(0, __float_as_int(x), 0x114, 0xf, 0xf, true);
    x += __int_as_float(v);
    v = __builtin_amdgcn_update_dpp(0, __float_as_int(x), 0x118, 0xf, 0xf, true);
    x += __int_as_float(v);
    v = __builtin_amdgcn_update_dpp(0, __float_as_int(x), 0x142, 0xa, 0xf, true);
    x += __int_as_float(v);
    v = __builtin_amdgcn_update_dpp(0, __float_as_int(x), 0x143, 0xc, 0xf, true);
    x += __int_as_float(v);
    return x;
}

__global__ __launch_bounds__(1024, 1) void lstm_rec(
    const float* __restrict__ Whh,   // [4096][1024]
    const float* __restrict__ xg,    // [8192][4096]
    float* __restrict__ hs,          // [(T+1)][1024] (rows 1..T used)
    u64* __restrict__ hdata)         // [2][1024] tagged {tag, f32}
{
    __shared__ float hinp[HID];      // h broadcast buffer

    const int tid = threadIdx.x;
    const int b   = blockIdx.x;          // 0..63
    const int w   = tid >> 6;            // wave 0..15
    const int l   = tid & 63;            // lane
    const int j   = b * NW + w;          // owned h index, 0..1023
    const int ju  = __builtin_amdgcn_readfirstlane(j);

    // Register-resident W_hh, flat layout: wreg[s][i] = W[s*1024+j][64i+l].
    float wreg[4][16];
#pragma unroll
    for (int s = 0; s < 4; ++s) {
        const float* row = &Whh[(size_t)(s * 1024 + j) * HID];
#pragma unroll
        for (int i = 0; i < 16; ++i) wreg[s][i] = row[64 * i + l];
    }
#pragma unroll
    for (int s = 0; s < 4; ++s)
#pragma unroll
        for (int i = 0; i < 16; ++i)
            asm volatile("" : "+v"(wreg[s][i]));

    // x-gates for t=0 (wave-uniform loads).
    float xv[4];
#pragma unroll
    for (int s = 0; s < 4; ++s)
        xv[s] = xg[(size_t)0 * G4 + s * 1024 + ju];

    float c = 0.f;                       // valid in lane 63 (all lanes carry)

    for (int t = 0; t < T_STEPS; ++t) {
        // ---- acquire h_{t-1}: 16-way sliced tagged-data poll ---------------
        if (t > 0) {
            const u64* base = hdata + (((size_t)(t - 1) & 1) << 10) + 64 * w;
            const uint32_t want32 = (uint32_t)t;
            u64 v;
            for (;;) {
                v = __hip_atomic_load(base + l, __ATOMIC_RELAXED,
                                      __HIP_MEMORY_SCOPE_AGENT);
                if (__all((uint32_t)(v >> 32) == want32)) break;
            }
            hinp[64 * w + l] = __uint_as_float((uint32_t)v);
        }
        __syncthreads();   // the ONE barrier per step

        float hval[16];
        if (t > 0) {
#pragma unroll
            for (int i = 0; i < 16; ++i) hval[i] = hinp[64 * i + l];
        } else {
#pragma unroll
            for (int i = 0; i < 16; ++i) hval[i] = 0.f;
        }

        // Prefetch next step's x-gates (wave-uniform; drained long before use).
        float xn[4] = {0.f, 0.f, 0.f, 0.f};
        if (t < T_STEPS - 1) {
#pragma unroll
            for (int s = 0; s < 4; ++s)
                xn[s] = xg[(size_t)(t + 1) * G4 + s * 1024 + ju];
        }

        // ---- gate dots + DPP reduction (sums valid in lane 63) -------------
        float gsum[4];
#pragma unroll
        for (int s = 0; s < 4; ++s) {
            float a = 0.f;
#pragma unroll
            for (int i = 0; i < 16; ++i) a = fmaf(wreg[s][i], hval[i], a);
            gsum[s] = dpp_reduce_add(a);
        }

        // Activations — only lane 63's values are meaningful.
        float ig = sigm_f(xv[0] + gsum[0]);
        float fg = sigm_f(xv[1] + gsum[1]);
        float gv = tanh_f(xv[2] + gsum[2]);
        float og = sigm_f(xv[3] + gsum[3]);
        c = fg * c + ig * gv;
        float h = og * tanh_f(c);

        // ---- publish: this wave's own h, directly from lane 63 -------------
        if (l == 63) {
            hs[(size_t)(t + 1) * HID + j] = h;               // epilogue copy
            u64 pub = ((u64)(uint32_t)(t + 1) << 32) | (u64)__float_as_uint(h);
            __hip_atomic_store(&hdata[(((size_t)t & 1) << 10) + j], pub,
                               __ATOMIC_RELAXED, __HIP_MEMORY_SCOPE_AGENT);
        }

#pragma unroll
        for (int s = 0; s < 4; ++s) xv[s] = xn[s];
    }
}

// ---------------------------------------------------------------------------
// Kernel 3: logits = hs @ W_lin^T + b_lin ; softmax over O=2.
// ---------------------------------------------------------------------------
__global__ __launch_bounds__(256) void proj_softmax(
    const float* __restrict__ hs,    // [(T+1)][1024], rows 1..T are h_t
    const float* __restrict__ Wl,    // [2][1024]
    const float* __restrict__ bl,    // [2]
    float* __restrict__ out)         // [T][2]
{
    const int tid = threadIdx.x;
    const int w = tid >> 6, l = tid & 63;
    const int row = blockIdx.x * 4 + w;            // 0..8191
    const float* h = &hs[(size_t)(row + 1) * HID];

    float a0 = 0.f, a1 = 0.f;
#pragma unroll
    for (int i = 0; i < 4; ++i) {
        float4 hv = *(const float4*)&h[256 * i + 4 * l];
        float4 w0 = *(const float4*)&Wl[256 * i + 4 * l];
        float4 w1 = *(const float4*)&Wl[HID + 256 * i + 4 * l];
        a0 = fmaf(hv.x, w0.x, a0); a0 = fmaf(hv.y, w0.y, a0);
        a0 = fmaf(hv.z, w0.z, a0); a0 = fmaf(hv.w, w0.w, a0);
        a1 = fmaf(hv.x, w1.x, a1); a1 = fmaf(hv.y, w1.y, a1);
        a1 = fmaf(hv.z, w1.z, a1); a1 = fmaf(hv.w, w1.w, a1);
    }
#pragma unroll
    for (int off = 1; off < 64; off <<= 1) {
        a0 += __shfl_xor(a0, off, 64);
        a1 += __shfl_xor(a1, off, 64);
    }
    if (l == 0) {
        float l0 = a0 + bl[0];
        float l1 = a1 + bl[1];
        float m  = fmaxf(l0, l1);
        float e0 = __expf(l0 - m), e1 = __expf(l1 - m);
        float inv = 1.f / (e0 + e1);
        float2 o = make_float2(e0 * inv, e1 * inv);
        *(float2*)&out[(size_t)row * 2] = o;
    }
}

// ---------------------------------------------------------------------------
extern "C" void kernel_launch(void* const* d_in, const int* in_sizes, int n_in,
                              void* d_out, int out_size, void* d_ws, size_t ws_size,
                              hipStream_t stream)
{
    const float* input = (const float*)d_in[0];   // [8192][512]
    const float* W_ih  = (const float*)d_in[1];   // [4096][512]
    const float* W_hh  = (const float*)d_in[2];   // [4096][1024]
    const float* b_ih  = (const float*)d_in[3];   // [4096]
    const float* b_hh  = (const float*)d_in[4];   // [4096]
    const float* W_lin = (const float*)d_in[5];   // [2][1024]
    const float* b_lin = (const float*)d_in[6];   // [2]
    float* out = (float*)d_out;                   // [8192][2]

    char* ws = (char*)d_ws;
    float* hs     = (float*)ws;                          // (T+1)*1024 f32
    size_t hs_b   = (size_t)(T_STEPS + 1) * HID * sizeof(float);
    u64*   hdata  = (u64*)(ws + hs_b);                   // 2*1024 u64
    size_t hd_b   = 2 * 1024 * sizeof(u64);
    float* xg     = (float*)(ws + hs_b + hd_b);          // T*4096 f32

    // No memsets needed: 0xAA poison (0xAAAAAAAA) never equals a valid tag
    // (1..8192), hs row 0 is never read, and t=0 uses in-register zeros.

    dim3 g1(G4 / 128, T_STEPS / 128);
    gemm_xgates<<<g1, 256, 0, stream>>>(input, W_ih, b_ih, b_hh, xg);

    lstm_rec<<<NBLK, NW * 64, 0, stream>>>(W_hh, xg, hs, hdata);

    proj_softmax<<<T_STEPS / 4, 256, 0, stream>>>(hs, W_lin, b_lin, out);
}

// Round 8
// 22382.547 us; speedup vs baseline: 1.1635x; 1.1635x over previous
//
#include <hip/hip_runtime.h>
#include <stdint.h>

#define T_STEPS 8192
#define IN_DIM  512
#define HID     1024
#define G4      4096
#define NBLK    64          // recurrent blocks (1 per CU, all co-resident)
#define NW      16          // waves per block

typedef unsigned long long u64;

// ---------------------------------------------------------------------------
// Kernel 1: x_gates[t][r] = sum_k input[t][k] * W_ih[r][k] + b_ih[r] + b_hh[r]
// fp32 tiled GEMM (NT), 128x128 tile, K-tile 8, 256 threads, 8x8 per thread.
// ---------------------------------------------------------------------------
__global__ __launch_bounds__(256) void gemm_xgates(
    const float* __restrict__ A,    // [8192][512]
    const float* __restrict__ W,    // [4096][512]
    const float* __restrict__ bih,  // [4096]
    const float* __restrict__ bhh,  // [4096]
    float* __restrict__ xg)         // [8192][4096]
{
    __shared__ float At[8][128];   // k-major A tile
    __shared__ float Bt[8][128];   // k-major W tile
    const int tid = threadIdx.x;
    const int r0 = blockIdx.x * 128;   // gate-row dim (4096)
    const int t0 = blockIdx.y * 128;   // time dim (8192)
    const int tx = tid & 15, ty = tid >> 4;
    const int lrow = tid >> 1;         // 0..127
    const int kq   = (tid & 1) * 4;    // 0 or 4

    float acc[8][8];
#pragma unroll
    for (int i = 0; i < 8; ++i)
#pragma unroll
        for (int j = 0; j < 8; ++j) acc[i][j] = 0.f;

    for (int k0 = 0; k0 < IN_DIM; k0 += 8) {
        float4 av = *(const float4*)&A[(size_t)(t0 + lrow) * IN_DIM + k0 + kq];
        float4 bv = *(const float4*)&W[(size_t)(r0 + lrow) * IN_DIM + k0 + kq];
        __syncthreads();
        At[kq + 0][lrow] = av.x; At[kq + 1][lrow] = av.y;
        At[kq + 2][lrow] = av.z; At[kq + 3][lrow] = av.w;
        Bt[kq + 0][lrow] = bv.x; Bt[kq + 1][lrow] = bv.y;
        Bt[kq + 2][lrow] = bv.z; Bt[kq + 3][lrow] = bv.w;
        __syncthreads();
#pragma unroll
        for (int k = 0; k < 8; ++k) {
            float4 a0 = *(const float4*)&At[k][ty * 8];
            float4 a1 = *(const float4*)&At[k][ty * 8 + 4];
            float4 b0 = *(const float4*)&Bt[k][tx * 8];
            float4 b1 = *(const float4*)&Bt[k][tx * 8 + 4];
            float aa[8] = {a0.x, a0.y, a0.z, a0.w, a1.x, a1.y, a1.z, a1.w};
            float bb[8] = {b0.x, b0.y, b0.z, b0.w, b1.x, b1.y, b1.z, b1.w};
#pragma unroll
            for (int i = 0; i < 8; ++i)
#pragma unroll
                for (int j = 0; j < 8; ++j) acc[i][j] += aa[i] * bb[j];
        }
    }

    float bias[8];
#pragma unroll
    for (int j = 0; j < 8; ++j) {
        int r = r0 + tx * 8 + j;
        bias[j] = bih[r] + bhh[r];
    }
#pragma unroll
    for (int i = 0; i < 8; ++i) {
        int t = t0 + ty * 8 + i;
        float4 o0 = make_float4(acc[i][0] + bias[0], acc[i][1] + bias[1],
                                acc[i][2] + bias[2], acc[i][3] + bias[3]);
        float4 o1 = make_float4(acc[i][4] + bias[4], acc[i][5] + bias[5],
                                acc[i][6] + bias[6], acc[i][7] + bias[7]);
        *(float4*)&xg[(size_t)t * G4 + r0 + tx * 8]     = o0;
        *(float4*)&xg[(size_t)t * G4 + r0 + tx * 8 + 4] = o1;
    }
}

// ---------------------------------------------------------------------------
// Kernel 2: persistent recurrent LSTM — R6 structure + paced polling.
//
// 64 blocks x 1024 threads (16 waves, 1 block/CU). Wave w owns h[16b+w] and
// its 4 gate rows; W_hh slice pinned in registers (64 f32/lane).
//
// Publish: wave0 lanes0-15 store 16 tagged u64 {tag=t+1, f32 h} as ONE 128B
// line into hdata[t&1] (R7 proved scattered publish costs ~1850 cyc/step:
// FETCH 435->715MB from per-update remote-L2 line refetch).
//
// Consume: waves0-3 poll their 256-slot quarter with tag check (data IS the
// flag — no fences). NEW: s_sleep pacing. In steady state a poller arrives
// ~2000+ cyc before data lands, and un-paced polling floods the 16 hot LLC
// lines with ~4K line-reads per 800-cyc sweep — the publish STORE to those
// same lines queues behind that read flood (R4's sentinel test couldn't
// falsify this: polling moved the flood onto the sentinel line itself).
// Pre-sleep ~1024 cyc (hidden: data isn't there yet) + ~384 cyc between
// failed checks cuts hot-line read pressure ~2.5-3x.
//
// Reduction: compiler-managed DPP chain (VALU pipe), sum in lane 63,
// broadcast via readlane.
// ---------------------------------------------------------------------------
__device__ __forceinline__ float sigm_f(float x) {
    return 1.f / (1.f + __expf(-x));
}
__device__ __forceinline__ float tanh_f(float x) {
    x = fminf(fmaxf(x, -15.f), 15.f);
    float e = __expf(2.f * x);
    return (e - 1.f) / (e + 1.f);
}

// Wave64 sum; result valid in lane 63 only. DPP ctrl: 0x110+N = row_shr:N,
// 0x142 = row_bcast:15, 0x143 = row_bcast:31. (R6-verified, compiler-managed.)
__device__ __forceinline__ float dpp_reduce_add(float x) {
    int v;
    v = __builtin_amdgcn_update_dpp(0, __float_as_int(x), 0x111, 0xf, 0xf, true);
    x += __int_as_float(v);
    v = __builtin_amdgcn_update_dpp(0, __float_as_int(x), 0x112, 0xf, 0xf, true);
    x += __int_as_float(v);
    v = __builtin_amdgcn_update_dpp(0, __float_as_int(x), 0x114, 0xf, 0xf, true);
    x += __int_as_float(v);
    v = __builtin_amdgcn_update_dpp(0, __float_as_int(x), 0x118, 0xf, 0xf, true);
    x += __int_as_float(v);
    v = __builtin_amdgcn_update_dpp(0, __float_as_int(x), 0x142, 0xa, 0xf, true);
    x += __int_as_float(v);
    v = __builtin_amdgcn_update_dpp(0, __float_as_int(x), 0x143, 0xc, 0xf, true);
    x += __int_as_float(v);
    return x;
}
__device__ __forceinline__ float lane63(float x) {
    return __uint_as_float(__builtin_amdgcn_readlane(__float_as_uint(x), 63));
}

__global__ __launch_bounds__(1024, 1) void lstm_rec(
    const float* __restrict__ Whh,   // [4096][1024]
    const float* __restrict__ xg,    // [8192][4096]
    float* __restrict__ hs,          // [(T+1)][1024] (rows 1..T used)
    u64* __restrict__ hdata)         // [2][1024] tagged {tag, f32}
{
    __shared__ float2 hinp2[512];    // pair-layout h broadcast buffer
    __shared__ float  hout[NW];

    const int tid = threadIdx.x;
    const int b   = blockIdx.x;          // 0..63
    const int w   = tid >> 6;            // wave 0..15
    const int l   = tid & 63;            // lane
    const int j   = b * NW + w;          // owned h index, 0..1023
    const int ju  = __builtin_amdgcn_readfirstlane(j);

    // Register-resident W_hh in pair layout: wreg2[s][i] = {W[row][128i+l],
    // W[row][128i+64+l]}, row = s*1024 + j.
    float2 wreg2[4][8];
#pragma unroll
    for (int s = 0; s < 4; ++s) {
        const float* row = &Whh[(size_t)(s * 1024 + j) * HID];
#pragma unroll
        for (int i = 0; i < 8; ++i) {
            wreg2[s][i].x = row[128 * i + l];
            wreg2[s][i].y = row[128 * i + 64 + l];
        }
    }
#pragma unroll
    for (int s = 0; s < 4; ++s)
#pragma unroll
        for (int i = 0; i < 8; ++i) {
            asm volatile("" : "+v"(wreg2[s][i].x));
            asm volatile("" : "+v"(wreg2[s][i].y));
        }

    // x-gates for t=0 (wave-uniform loads).
    float xv[4];
#pragma unroll
    for (int s = 0; s < 4; ++s)
        xv[s] = xg[(size_t)0 * G4 + s * 1024 + ju];

    float c = 0.f;

    for (int t = 0; t < T_STEPS; ++t) {
        // ---- acquire h_{t-1}: paced tagged-data poll -----------------------
        if (t > 0 && w < 4) {
            const u64* base = hdata + (((size_t)(t - 1) & 1) << 10) + 256 * w;
            const u64 want = (u64)(uint32_t)t;
            u64 v0, v1, v2, v3;
            // We arrive well before data in steady state; don't flood the LLC.
            __builtin_amdgcn_s_sleep(16);            // ~1024 cyc, hidden
            for (;;) {
                v0 = __hip_atomic_load(base + l,       __ATOMIC_RELAXED, __HIP_MEMORY_SCOPE_AGENT);
                v1 = __hip_atomic_load(base + 64 + l,  __ATOMIC_RELAXED, __HIP_MEMORY_SCOPE_AGENT);
                v2 = __hip_atomic_load(base + 128 + l, __ATOMIC_RELAXED, __HIP_MEMORY_SCOPE_AGENT);
                v3 = __hip_atomic_load(base + 192 + l, __ATOMIC_RELAXED, __HIP_MEMORY_SCOPE_AGENT);
                bool ok = ((v0 >> 32) == want) & ((v1 >> 32) == want) &
                          ((v2 >> 32) == want) & ((v3 >> 32) == want);
                if (__all(ok)) break;
                __builtin_amdgcn_s_sleep(6);         // ~384 cyc between checks
            }
            // Deposit payloads in pair layout: quarter w covers h[256w..256w+256):
            hinp2[128 * w + l] = make_float2(__uint_as_float((uint32_t)v0),
                                             __uint_as_float((uint32_t)v1));
            hinp2[128 * w + 64 + l] = make_float2(__uint_as_float((uint32_t)v2),
                                                  __uint_as_float((uint32_t)v3));
        }
        __syncthreads();   // barrier A: h broadcast ready (or t==0)

        float2 hval2[8];
        if (t > 0) {
#pragma unroll
            for (int i = 0; i < 8; ++i) hval2[i] = hinp2[64 * i + l];
        } else {
#pragma unroll
            for (int i = 0; i < 8; ++i) hval2[i] = make_float2(0.f, 0.f);
        }

        // Prefetch next step's x-gates (wave-uniform; drained long before use).
        float xn[4] = {0.f, 0.f, 0.f, 0.f};
        if (t < T_STEPS - 1) {
#pragma unroll
            for (int s = 0; s < 4; ++s)
                xn[s] = xg[(size_t)(t + 1) * G4 + s * 1024 + ju];
        }

        // ---- gate dots (packed fp32) + DPP reduction -----------------------
        float gsum[4];
#pragma unroll
        for (int s = 0; s < 4; ++s) {
            float2 a2 = make_float2(0.f, 0.f);
#pragma unroll
            for (int i = 0; i < 8; ++i) {
                a2.x = fmaf(wreg2[s][i].x, hval2[i].x, a2.x);
                a2.y = fmaf(wreg2[s][i].y, hval2[i].y, a2.y);
            }
            gsum[s] = lane63(dpp_reduce_add(a2.x + a2.y));
        }

        float ig = sigm_f(xv[0] + gsum[0]);
        float fg = sigm_f(xv[1] + gsum[1]);
        float gv = tanh_f(xv[2] + gsum[2]);
        float og = sigm_f(xv[3] + gsum[3]);
        c = fg * c + ig * gv;                // wave-uniform
        float h = og * tanh_f(c);

        if (l == 0) hout[w] = h;
        __syncthreads();   // barrier B: hout complete

        // ---- publish: one 128B line from wave 0 ----------------------------
        if (w == 0 && l < NW) {
            float hv = hout[l];
            hs[(size_t)(t + 1) * HID + b * NW + l] = hv;     // epilogue copy
            u64 pub = ((u64)(uint32_t)(t + 1) << 32) | (u64)__float_as_uint(hv);
            __hip_atomic_store(&hdata[(((size_t)t & 1) << 10) + b * NW + l], pub,
                               __ATOMIC_RELAXED, __HIP_MEMORY_SCOPE_AGENT);
        }

#pragma unroll
        for (int s = 0; s < 4; ++s) xv[s] = xn[s];
    }
}

// ---------------------------------------------------------------------------
// Kernel 3: logits = hs @ W_lin^T + b_lin ; softmax over O=2.
// ---------------------------------------------------------------------------
__global__ __launch_bounds__(256) void proj_softmax(
    const float* __restrict__ hs,    // [(T+1)][1024], rows 1..T are h_t
    const float* __restrict__ Wl,    // [2][1024]
    const float* __restrict__ bl,    // [2]
    float* __restrict__ out)         // [T][2]
{
    const int tid = threadIdx.x;
    const int w = tid >> 6, l = tid & 63;
    const int row = blockIdx.x * 4 + w;            // 0..8191
    const float* h = &hs[(size_t)(row + 1) * HID];

    float a0 = 0.f, a1 = 0.f;
#pragma unroll
    for (int i = 0; i < 4; ++i) {
        float4 hv = *(const float4*)&h[256 * i + 4 * l];
        float4 w0 = *(const float4*)&Wl[256 * i + 4 * l];
        float4 w1 = *(const float4*)&Wl[HID + 256 * i + 4 * l];
        a0 = fmaf(hv.x, w0.x, a0); a0 = fmaf(hv.y, w0.y, a0);
        a0 = fmaf(hv.z, w0.z, a0); a0 = fmaf(hv.w, w0.w, a0);
        a1 = fmaf(hv.x, w1.x, a1); a1 = fmaf(hv.y, w1.y, a1);
        a1 = fmaf(hv.z, w1.z, a1); a1 = fmaf(hv.w, w1.w, a1);
    }
#pragma unroll
    for (int off = 1; off < 64; off <<= 1) {
        a0 += __shfl_xor(a0, off, 64);
        a1 += __shfl_xor(a1, off, 64);
    }
    if (l == 0) {
        float l0 = a0 + bl[0];
        float l1 = a1 + bl[1];
        float m  = fmaxf(l0, l1);
        float e0 = __expf(l0 - m), e1 = __expf(l1 - m);
        float inv = 1.f / (e0 + e1);
        float2 o = make_float2(e0 * inv, e1 * inv);
        *(float2*)&out[(size_t)row * 2] = o;
    }
}

// ---------------------------------------------------------------------------
extern "C" void kernel_launch(void* const* d_in, const int* in_sizes, int n_in,
                              void* d_out, int out_size, void* d_ws, size_t ws_size,
                              hipStream_t stream)
{
    const float* input = (const float*)d_in[0];   // [8192][512]
    const float* W_ih  = (const float*)d_in[1];   // [4096][512]
    const float* W_hh  = (const float*)d_in[2];   // [4096][1024]
    const float* b_ih  = (const float*)d_in[3];   // [4096]
    const float* b_hh  = (const float*)d_in[4];   // [4096]
    const float* W_lin = (const float*)d_in[5];   // [2][1024]
    const float* b_lin = (const float*)d_in[6];   // [2]
    float* out = (float*)d_out;                   // [8192][2]

    char* ws = (char*)d_ws;
    float* hs     = (float*)ws;                          // (T+1)*1024 f32
    size_t hs_b   = (size_t)(T_STEPS + 1) * HID * sizeof(float);
    u64*   hdata  = (u64*)(ws + hs_b);                   // 2*1024 u64
    size_t hd_b   = 2 * 1024 * sizeof(u64);
    float* xg     = (float*)(ws + hs_b + hd_b);          // T*4096 f32

    // No memsets needed: 0xAA poison (0xAAAAAAAA) never equals a valid tag
    // (1..8192), hs row 0 is never read, and t=0 uses in-register zeros.

    dim3 g1(G4 / 128, T_STEPS / 128);
    gemm_xgates<<<g1, 256, 0, stream>>>(input, W_ih, b_ih, b_hh, xg);

    lstm_rec<<<NBLK, NW * 64, 0, stream>>>(W_hh, xg, hs, hdata);

    proj_softmax<<<T_STEPS / 4, 256, 0, stream>>>(hs, W_lin, b_lin, out);
}

// Round 9
// 22006.911 us; speedup vs baseline: 1.1834x; 1.0171x over previous
//
#include <hip/hip_runtime.h>
#include <stdint.h>

#define T_STEPS 8192
#define IN_DIM  512
#define HID     1024
#define G4      4096
#define NBLK    64          // recurrent blocks (1 per CU, all co-resident)
#define NW      16          // waves per block

typedef unsigned long long u64;

// ---------------------------------------------------------------------------
// Kernel 1: x_gates[t][r] = sum_k input[t][k] * W_ih[r][k] + b_ih[r] + b_hh[r]
// fp32 tiled GEMM (NT), 128x128 tile, K-tile 8, 256 threads, 8x8 per thread.
// ---------------------------------------------------------------------------
__global__ __launch_bounds__(256) void gemm_xgates(
    const float* __restrict__ A,    // [8192][512]
    const float* __restrict__ W,    // [4096][512]
    const float* __restrict__ bih,  // [4096]
    const float* __restrict__ bhh,  // [4096]
    float* __restrict__ xg)         // [8192][4096]
{
    __shared__ float At[8][128];   // k-major A tile
    __shared__ float Bt[8][128];   // k-major W tile
    const int tid = threadIdx.x;
    const int r0 = blockIdx.x * 128;   // gate-row dim (4096)
    const int t0 = blockIdx.y * 128;   // time dim (8192)
    const int tx = tid & 15, ty = tid >> 4;
    const int lrow = tid >> 1;         // 0..127
    const int kq   = (tid & 1) * 4;    // 0 or 4

    float acc[8][8];
#pragma unroll
    for (int i = 0; i < 8; ++i)
#pragma unroll
        for (int j = 0; j < 8; ++j) acc[i][j] = 0.f;

    for (int k0 = 0; k0 < IN_DIM; k0 += 8) {
        float4 av = *(const float4*)&A[(size_t)(t0 + lrow) * IN_DIM + k0 + kq];
        float4 bv = *(const float4*)&W[(size_t)(r0 + lrow) * IN_DIM + k0 + kq];
        __syncthreads();
        At[kq + 0][lrow] = av.x; At[kq + 1][lrow] = av.y;
        At[kq + 2][lrow] = av.z; At[kq + 3][lrow] = av.w;
        Bt[kq + 0][lrow] = bv.x; Bt[kq + 1][lrow] = bv.y;
        Bt[kq + 2][lrow] = bv.z; Bt[kq + 3][lrow] = bv.w;
        __syncthreads();
#pragma unroll
        for (int k = 0; k < 8; ++k) {
            float4 a0 = *(const float4*)&At[k][ty * 8];
            float4 a1 = *(const float4*)&At[k][ty * 8 + 4];
            float4 b0 = *(const float4*)&Bt[k][tx * 8];
            float4 b1 = *(const float4*)&Bt[k][tx * 8 + 4];
            float aa[8] = {a0.x, a0.y, a0.z, a0.w, a1.x, a1.y, a1.z, a1.w};
            float bb[8] = {b0.x, b0.y, b0.z, b0.w, b1.x, b1.y, b1.z, b1.w};
#pragma unroll
            for (int i = 0; i < 8; ++i)
#pragma unroll
                for (int j = 0; j < 8; ++j) acc[i][j] += aa[i] * bb[j];
        }
    }

    float bias[8];
#pragma unroll
    for (int j = 0; j < 8; ++j) {
        int r = r0 + tx * 8 + j;
        bias[j] = bih[r] + bhh[r];
    }
#pragma unroll
    for (int i = 0; i < 8; ++i) {
        int t = t0 + ty * 8 + i;
        float4 o0 = make_float4(acc[i][0] + bias[0], acc[i][1] + bias[1],
                                acc[i][2] + bias[2], acc[i][3] + bias[3]);
        float4 o1 = make_float4(acc[i][4] + bias[4], acc[i][5] + bias[5],
                                acc[i][6] + bias[6], acc[i][7] + bias[7]);
        *(float4*)&xg[(size_t)t * G4 + r0 + tx * 8]     = o0;
        *(float4*)&xg[(size_t)t * G4 + r0 + tx * 8 + 4] = o1;
    }
}

// ---------------------------------------------------------------------------
// Kernel 2: persistent recurrent LSTM — R6 baseline + fast 16-way poll.
//
// 64 blocks x 1024 threads (16 waves, 1 block/CU). Wave w owns h[16b+w] and
// its 4 gate rows; W_hh slice pinned in registers (64 f32/lane).
//
// Publish: wave0 lanes0-15 store 16 tagged u64 {tag=t+1, f32 h} as ONE 128B
// line (R7 proved scattered publish costs ~1850 cyc/step). Wave1 does the hs
// epilogue copy so the publishing wave's path is minimal.
//
// Consume: ALL 16 waves poll: wave w spins on its own 64-slot slice with ONE
// dwordx2 load per lane per iteration (~350 cyc/iter vs ~800 for the R6
// 4-load sweep) -> halves observation quantization and the tail skew it
// feeds. Deposit into float2 pair layout (even waves .x, odd waves .y;
// stride-8 = 2-way bank alias = free). Data IS the flag; no fences; parity
// double-buffer safe by transitivity.
// ---------------------------------------------------------------------------
__device__ __forceinline__ float sigm_f(float x) {
    return 1.f / (1.f + __expf(-x));
}
__device__ __forceinline__ float tanh_f(float x) {
    x = fminf(fmaxf(x, -15.f), 15.f);
    float e = __expf(2.f * x);
    return (e - 1.f) / (e + 1.f);
}

// Wave64 sum; result valid in lane 63 only. DPP ctrl: 0x110+N = row_shr:N,
// 0x142 = row_bcast:15, 0x143 = row_bcast:31. (R6-verified, compiler-managed.)
__device__ __forceinline__ float dpp_reduce_add(float x) {
    int v;
    v = __builtin_amdgcn_update_dpp(0, __float_as_int(x), 0x111, 0xf, 0xf, true);
    x += __int_as_float(v);
    v = __builtin_amdgcn_update_dpp(0, __float_as_int(x), 0x112, 0xf, 0xf, true);
    x += __int_as_float(v);
    v = __builtin_amdgcn_update_dpp(0, __float_as_int(x), 0x114, 0xf, 0xf, true);
    x += __int_as_float(v);
    v = __builtin_amdgcn_update_dpp(0, __float_as_int(x), 0x118, 0xf, 0xf, true);
    x += __int_as_float(v);
    v = __builtin_amdgcn_update_dpp(0, __float_as_int(x), 0x142, 0xa, 0xf, true);
    x += __int_as_float(v);
    v = __builtin_amdgcn_update_dpp(0, __float_as_int(x), 0x143, 0xc, 0xf, true);
    x += __int_as_float(v);
    return x;
}
__device__ __forceinline__ float lane63(float x) {
    return __uint_as_float(__builtin_amdgcn_readlane(__float_as_uint(x), 63));
}

__global__ __launch_bounds__(1024, 1) void lstm_rec(
    const float* __restrict__ Whh,   // [4096][1024]
    const float* __restrict__ xg,    // [8192][4096]
    float* __restrict__ hs,          // [(T+1)][1024] (rows 1..T used)
    u64* __restrict__ hdata)         // [2][1024] tagged {tag, f32}
{
    __shared__ float2 hinp2[512];    // pair-layout h broadcast buffer
    __shared__ float  hout[NW];

    const int tid = threadIdx.x;
    const int b   = blockIdx.x;          // 0..63
    const int w   = tid >> 6;            // wave 0..15
    const int l   = tid & 63;            // lane
    const int j   = b * NW + w;          // owned h index, 0..1023
    const int ju  = __builtin_amdgcn_readfirstlane(j);

    // Register-resident W_hh in pair layout: wreg2[s][i] = {W[row][128i+l],
    // W[row][128i+64+l]}, row = s*1024 + j.
    float2 wreg2[4][8];
#pragma unroll
    for (int s = 0; s < 4; ++s) {
        const float* row = &Whh[(size_t)(s * 1024 + j) * HID];
#pragma unroll
        for (int i = 0; i < 8; ++i) {
            wreg2[s][i].x = row[128 * i + l];
            wreg2[s][i].y = row[128 * i + 64 + l];
        }
    }
#pragma unroll
    for (int s = 0; s < 4; ++s)
#pragma unroll
        for (int i = 0; i < 8; ++i) {
            asm volatile("" : "+v"(wreg2[s][i].x));
            asm volatile("" : "+v"(wreg2[s][i].y));
        }

    // x-gates for t=0 (wave-uniform loads).
    float xv[4];
#pragma unroll
    for (int s = 0; s < 4; ++s)
        xv[s] = xg[(size_t)0 * G4 + s * 1024 + ju];

    float c = 0.f;

    for (int t = 0; t < T_STEPS; ++t) {
        // ---- acquire h_{t-1}: 16-way sliced fast poll ----------------------
        if (t > 0) {
            const u64* base = hdata + (((size_t)(t - 1) & 1) << 10) + 64 * w;
            const uint32_t want32 = (uint32_t)t;
            u64 v;
            for (;;) {
                v = __hip_atomic_load(base + l, __ATOMIC_RELAXED,
                                      __HIP_MEMORY_SCOPE_AGENT);
                if (__all((uint32_t)(v >> 32) == want32)) break;
            }
            // Wave w's slice is h[64w .. 64w+63]. Pair layout:
            // hinp2[64i + l] = {h[128i + l], h[128i + 64 + l]}
            //   w even (w=2i): our value is the .x component of hinp2[64i+l]
            //   w odd  (w=2i+1): the .y component.
            float* comp = (float*)&hinp2[64 * (w >> 1) + l];
            comp[w & 1] = __uint_as_float((uint32_t)v);
        }
        __syncthreads();   // barrier A: h broadcast ready (or t==0)

        float2 hval2[8];
        if (t > 0) {
#pragma unroll
            for (int i = 0; i < 8; ++i) hval2[i] = hinp2[64 * i + l];
        } else {
#pragma unroll
            for (int i = 0; i < 8; ++i) hval2[i] = make_float2(0.f, 0.f);
        }

        // Prefetch next step's x-gates (wave-uniform; drained long before use).
        float xn[4] = {0.f, 0.f, 0.f, 0.f};
        if (t < T_STEPS - 1) {
#pragma unroll
            for (int s = 0; s < 4; ++s)
                xn[s] = xg[(size_t)(t + 1) * G4 + s * 1024 + ju];
        }

        // ---- gate dots (packed fp32) + DPP reduction -----------------------
        float gsum[4];
#pragma unroll
        for (int s = 0; s < 4; ++s) {
            float2 a2 = make_float2(0.f, 0.f);
#pragma unroll
            for (int i = 0; i < 8; ++i) {
                a2.x = fmaf(wreg2[s][i].x, hval2[i].x, a2.x);
                a2.y = fmaf(wreg2[s][i].y, hval2[i].y, a2.y);
            }
            gsum[s] = lane63(dpp_reduce_add(a2.x + a2.y));
        }

        float ig = sigm_f(xv[0] + gsum[0]);
        float fg = sigm_f(xv[1] + gsum[1]);
        float gv = tanh_f(xv[2] + gsum[2]);
        float og = sigm_f(xv[3] + gsum[3]);
        c = fg * c + ig * gv;                // wave-uniform
        float h = og * tanh_f(c);

        if (l == 0) hout[w] = h;
        __syncthreads();   // barrier B: hout complete

        // ---- publish: one 128B line from wave 0; hs copy from wave 1 -------
        if (w == 0 && l < NW) {
            u64 pub = ((u64)(uint32_t)(t + 1) << 32)
                    | (u64)__float_as_uint(hout[l]);
            __hip_atomic_store(&hdata[(((size_t)t & 1) << 10) + b * NW + l], pub,
                               __ATOMIC_RELAXED, __HIP_MEMORY_SCOPE_AGENT);
        } else if (w == 1 && l < NW) {
            hs[(size_t)(t + 1) * HID + b * NW + l] = hout[l];   // epilogue copy
        }

#pragma unroll
        for (int s = 0; s < 4; ++s) xv[s] = xn[s];
    }
}

// ---------------------------------------------------------------------------
// Kernel 3: logits = hs @ W_lin^T + b_lin ; softmax over O=2.
// ---------------------------------------------------------------------------
__global__ __launch_bounds__(256) void proj_softmax(
    const float* __restrict__ hs,    // [(T+1)][1024], rows 1..T are h_t
    const float* __restrict__ Wl,    // [2][1024]
    const float* __restrict__ bl,    // [2]
    float* __restrict__ out)         // [T][2]
{
    const int tid = threadIdx.x;
    const int w = tid >> 6, l = tid & 63;
    const int row = blockIdx.x * 4 + w;            // 0..8191
    const float* h = &hs[(size_t)(row + 1) * HID];

    float a0 = 0.f, a1 = 0.f;
#pragma unroll
    for (int i = 0; i < 4; ++i) {
        float4 hv = *(const float4*)&h[256 * i + 4 * l];
        float4 w0 = *(const float4*)&Wl[256 * i + 4 * l];
        float4 w1 = *(const float4*)&Wl[HID + 256 * i + 4 * l];
        a0 = fmaf(hv.x, w0.x, a0); a0 = fmaf(hv.y, w0.y, a0);
        a0 = fmaf(hv.z, w0.z, a0); a0 = fmaf(hv.w, w0.w, a0);
        a1 = fmaf(hv.x, w1.x, a1); a1 = fmaf(hv.y, w1.y, a1);
        a1 = fmaf(hv.z, w1.z, a1); a1 = fmaf(hv.w, w1.w, a1);
    }
#pragma unroll
    for (int off = 1; off < 64; off <<= 1) {
        a0 += __shfl_xor(a0, off, 64);
        a1 += __shfl_xor(a1, off, 64);
    }
    if (l == 0) {
        float l0 = a0 + bl[0];
        float l1 = a1 + bl[1];
        float m  = fmaxf(l0, l1);
        float e0 = __expf(l0 - m), e1 = __expf(l1 - m);
        float inv = 1.f / (e0 + e1);
        float2 o = make_float2(e0 * inv, e1 * inv);
        *(float2*)&out[(size_t)row * 2] = o;
    }
}

// ---------------------------------------------------------------------------
extern "C" void kernel_launch(void* const* d_in, const int* in_sizes, int n_in,
                              void* d_out, int out_size, void* d_ws, size_t ws_size,
                              hipStream_t stream)
{
    const float* input = (const float*)d_in[0];   // [8192][512]
    const float* W_ih  = (const float*)d_in[1];   // [4096][512]
    const float* W_hh  = (const float*)d_in[2];   // [4096][1024]
    const float* b_ih  = (const float*)d_in[3];   // [4096]
    const float* b_hh  = (const float*)d_in[4];   // [4096]
    const float* W_lin = (const float*)d_in[5];   // [2][1024]
    const float* b_lin = (const float*)d_in[6];   // [2]
    float* out = (float*)d_out;                   // [8192][2]

    char* ws = (char*)d_ws;
    float* hs     = (float*)ws;                          // (T+1)*1024 f32
    size_t hs_b   = (size_t)(T_STEPS + 1) * HID * sizeof(float);
    u64*   hdata  = (u64*)(ws + hs_b);                   // 2*1024 u64
    size_t hd_b   = 2 * 1024 * sizeof(u64);
    float* xg     = (float*)(ws + hs_b + hd_b);          // T*4096 f32

    // No memsets needed: 0xAA poison (0xAAAAAAAA) never equals a valid tag
    // (1..8192), hs row 0 is never read, and t=0 uses in-register zeros.

    dim3 g1(G4 / 128, T_STEPS / 128);
    gemm_xgates<<<g1, 256, 0, stream>>>(input, W_ih, b_ih, b_hh, xg);

    lstm_rec<<<NBLK, NW * 64, 0, stream>>>(W_hh, xg, hs, hdata);

    proj_softmax<<<T_STEPS / 4, 256, 0, stream>>>(hs, W_lin, b_lin, out);
}

// Round 10
// 18119.490 us; speedup vs baseline: 1.4373x; 1.2145x over previous
//
#include <hip/hip_runtime.h>
#include <stdint.h>

#define T_STEPS 8192
#define IN_DIM  512
#define HID     1024
#define G4      4096
#define NBLK    64          // recurrent blocks (1 per CU, all co-resident)
#define NW      16          // waves per block

typedef unsigned long long u64;

// ---------------------------------------------------------------------------
// Kernel 1: x_gates[t][r] = sum_k input[t][k] * W_ih[r][k] + b_ih[r] + b_hh[r]
// fp32 tiled GEMM (NT), 128x128 tile, K-tile 8, 256 threads, 8x8 per thread.
// ---------------------------------------------------------------------------
__global__ __launch_bounds__(256) void gemm_xgates(
    const float* __restrict__ A,    // [8192][512]
    const float* __restrict__ W,    // [4096][512]
    const float* __restrict__ bih,  // [4096]
    const float* __restrict__ bhh,  // [4096]
    float* __restrict__ xg)         // [8192][4096]
{
    __shared__ float At[8][128];   // k-major A tile
    __shared__ float Bt[8][128];   // k-major W tile
    const int tid = threadIdx.x;
    const int r0 = blockIdx.x * 128;   // gate-row dim (4096)
    const int t0 = blockIdx.y * 128;   // time dim (8192)
    const int tx = tid & 15, ty = tid >> 4;
    const int lrow = tid >> 1;         // 0..127
    const int kq   = (tid & 1) * 4;    // 0 or 4

    float acc[8][8];
#pragma unroll
    for (int i = 0; i < 8; ++i)
#pragma unroll
        for (int j = 0; j < 8; ++j) acc[i][j] = 0.f;

    for (int k0 = 0; k0 < IN_DIM; k0 += 8) {
        float4 av = *(const float4*)&A[(size_t)(t0 + lrow) * IN_DIM + k0 + kq];
        float4 bv = *(const float4*)&W[(size_t)(r0 + lrow) * IN_DIM + k0 + kq];
        __syncthreads();
        At[kq + 0][lrow] = av.x; At[kq + 1][lrow] = av.y;
        At[kq + 2][lrow] = av.z; At[kq + 3][lrow] = av.w;
        Bt[kq + 0][lrow] = bv.x; Bt[kq + 1][lrow] = bv.y;
        Bt[kq + 2][lrow] = bv.z; Bt[kq + 3][lrow] = bv.w;
        __syncthreads();
#pragma unroll
        for (int k = 0; k < 8; ++k) {
            float4 a0 = *(const float4*)&At[k][ty * 8];
            float4 a1 = *(const float4*)&At[k][ty * 8 + 4];
            float4 b0 = *(const float4*)&Bt[k][tx * 8];
            float4 b1 = *(const float4*)&Bt[k][tx * 8 + 4];
            float aa[8] = {a0.x, a0.y, a0.z, a0.w, a1.x, a1.y, a1.z, a1.w};
            float bb[8] = {b0.x, b0.y, b0.z, b0.w, b1.x, b1.y, b1.z, b1.w};
#pragma unroll
            for (int i = 0; i < 8; ++i)
#pragma unroll
                for (int j = 0; j < 8; ++j) acc[i][j] += aa[i] * bb[j];
        }
    }

    float bias[8];
#pragma unroll
    for (int j = 0; j < 8; ++j) {
        int r = r0 + tx * 8 + j;
        bias[j] = bih[r] + bhh[r];
    }
#pragma unroll
    for (int i = 0; i < 8; ++i) {
        int t = t0 + ty * 8 + i;
        float4 o0 = make_float4(acc[i][0] + bias[0], acc[i][1] + bias[1],
                                acc[i][2] + bias[2], acc[i][3] + bias[3]);
        float4 o1 = make_float4(acc[i][4] + bias[4], acc[i][5] + bias[5],
                                acc[i][6] + bias[6], acc[i][7] + bias[7]);
        *(float4*)&xg[(size_t)t * G4 + r0 + tx * 8]     = o0;
        *(float4*)&xg[(size_t)t * G4 + r0 + tx * 8 + 4] = o1;
    }
}

// ---------------------------------------------------------------------------
// Kernel 2: persistent recurrent LSTM — R6 comm core, barrier-B-free publish,
// rcp-based activations.
//
// 64 blocks x 1024 threads (16 waves, 1 block/CU). Wave w owns h[16b+w] and
// its 4 gate rows; W_hh slice pinned in registers (64 f32/lane).
//
// Consume (R6-proven): waves 0-3 poll their 256-slot quarter (4 tagged-u64
// loads/lane/iter — R9 showed narrower polls don't help: iteration cost is
// one LLC RT either way). Deposit float2 pair layout into parity-double-
// buffered hinp2. ONE barrier per step (A). Double-buffer safety: writes to
// buf p at iter t+2 are program-ordered after barrier A(t+1), which is after
// all iter-t readers of buf p finished.
//
// Publish (new): lane 63 of each wave drops {h, tag=t+1} into LDS (release).
// Wave 4 (non-polling) spin-gathers the 16 tags (~80cyc LDS iters), then
// stores the 16 tagged u64 as ONE 128B line (R7: single-line publish is
// load-bearing) + the hs epilogue copy. Polling waves go straight from dot
// to polling t+1 — no barrier B, no gather on their critical path. hout
// single-buffer is safe: barrier A(t+1) requires the gatherer to have
// finished gather(t) before any producer can rewrite its slot at t+1.
//
// Activations: v_rcp_f32 instead of full-precision fp32 division (5 divides
// x ~10 instr each were hiding in sigmoid/tanh). ~1ulp; threshold 1.45e-2.
// ---------------------------------------------------------------------------
__device__ __forceinline__ float sigm_f(float x) {
    return __builtin_amdgcn_rcpf(1.f + __expf(-x));
}
__device__ __forceinline__ float tanh_f(float x) {
    x = fminf(fmaxf(x, -15.f), 15.f);
    float e = __expf(2.f * x);
    return (e - 1.f) * __builtin_amdgcn_rcpf(e + 1.f);
}

// Wave64 sum; result valid in lane 63 only. DPP ctrl: 0x110+N = row_shr:N,
// 0x142 = row_bcast:15, 0x143 = row_bcast:31. (R6-verified, compiler-managed.)
__device__ __forceinline__ float dpp_reduce_add(float x) {
    int v;
    v = __builtin_amdgcn_update_dpp(0, __float_as_int(x), 0x111, 0xf, 0xf, true);
    x += __int_as_float(v);
    v = __builtin_amdgcn_update_dpp(0, __float_as_int(x), 0x112, 0xf, 0xf, true);
    x += __int_as_float(v);
    v = __builtin_amdgcn_update_dpp(0, __float_as_int(x), 0x114, 0xf, 0xf, true);
    x += __int_as_float(v);
    v = __builtin_amdgcn_update_dpp(0, __float_as_int(x), 0x118, 0xf, 0xf, true);
    x += __int_as_float(v);
    v = __builtin_amdgcn_update_dpp(0, __float_as_int(x), 0x142, 0xa, 0xf, true);
    x += __int_as_float(v);
    v = __builtin_amdgcn_update_dpp(0, __float_as_int(x), 0x143, 0xc, 0xf, true);
    x += __int_as_float(v);
    return x;
}

__global__ __launch_bounds__(1024, 1) void lstm_rec(
    const float* __restrict__ Whh,   // [4096][1024]
    const float* __restrict__ xg,    // [8192][4096]
    float* __restrict__ hs,          // [(T+1)][1024] (rows 1..T used)
    u64* __restrict__ hdata)         // [2][1024] tagged {tag, f32}
{
    __shared__ float2   hinp2[2][512];   // parity-buffered h broadcast
    __shared__ float    hout_h[NW];
    __shared__ uint32_t hout_tag[NW];

    const int tid = threadIdx.x;
    const int b   = blockIdx.x;          // 0..63
    const int w   = tid >> 6;            // wave 0..15
    const int l   = tid & 63;            // lane
    const int j   = b * NW + w;          // owned h index, 0..1023
    const int ju  = __builtin_amdgcn_readfirstlane(j);

    if (tid < NW) hout_tag[tid] = 0;     // ordered by barrier A of iter 0

    // Register-resident W_hh in pair layout: wreg2[s][i] = {W[row][128i+l],
    // W[row][128i+64+l]}, row = s*1024 + j.
    float2 wreg2[4][8];
#pragma unroll
    for (int s = 0; s < 4; ++s) {
        const float* row = &Whh[(size_t)(s * 1024 + j) * HID];
#pragma unroll
        for (int i = 0; i < 8; ++i) {
            wreg2[s][i].x = row[128 * i + l];
            wreg2[s][i].y = row[128 * i + 64 + l];
        }
    }
#pragma unroll
    for (int s = 0; s < 4; ++s)
#pragma unroll
        for (int i = 0; i < 8; ++i) {
            asm volatile("" : "+v"(wreg2[s][i].x));
            asm volatile("" : "+v"(wreg2[s][i].y));
        }

    // x-gates for t=0 (wave-uniform loads).
    float xv[4];
#pragma unroll
    for (int s = 0; s < 4; ++s)
        xv[s] = xg[(size_t)0 * G4 + s * 1024 + ju];

    float c = 0.f;                       // meaningful in lane 63 only

    for (int t = 0; t < T_STEPS; ++t) {
        const int buf = t & 1;
        // ---- acquire h_{t-1}: 4-wave x 4-load tagged poll (R6-proven) ------
        if (t > 0 && w < 4) {
            const u64* base = hdata + (((size_t)(t - 1) & 1) << 10) + 256 * w;
            const u64 want = (u64)(uint32_t)t;
            u64 v0, v1, v2, v3;
            for (;;) {
                v0 = __hip_atomic_load(base + l,       __ATOMIC_RELAXED, __HIP_MEMORY_SCOPE_AGENT);
                v1 = __hip_atomic_load(base + 64 + l,  __ATOMIC_RELAXED, __HIP_MEMORY_SCOPE_AGENT);
                v2 = __hip_atomic_load(base + 128 + l, __ATOMIC_RELAXED, __HIP_MEMORY_SCOPE_AGENT);
                v3 = __hip_atomic_load(base + 192 + l, __ATOMIC_RELAXED, __HIP_MEMORY_SCOPE_AGENT);
                bool ok = ((v0 >> 32) == want) & ((v1 >> 32) == want) &
                          ((v2 >> 32) == want) & ((v3 >> 32) == want);
                if (__all(ok)) break;
            }
            hinp2[buf][128 * w + l] = make_float2(__uint_as_float((uint32_t)v0),
                                                  __uint_as_float((uint32_t)v1));
            hinp2[buf][128 * w + 64 + l] = make_float2(__uint_as_float((uint32_t)v2),
                                                       __uint_as_float((uint32_t)v3));
        }
        __syncthreads();   // barrier A: the ONE barrier per step

        float2 hval2[8];
        if (t > 0) {
#pragma unroll
            for (int i = 0; i < 8; ++i) hval2[i] = hinp2[buf][64 * i + l];
        } else {
#pragma unroll
            for (int i = 0; i < 8; ++i) hval2[i] = make_float2(0.f, 0.f);
        }

        // Prefetch next step's x-gates (wave-uniform; drained long before use).
        float xn[4] = {0.f, 0.f, 0.f, 0.f};
        if (t < T_STEPS - 1) {
#pragma unroll
            for (int s = 0; s < 4; ++s)
                xn[s] = xg[(size_t)(t + 1) * G4 + s * 1024 + ju];
        }

        // ---- gate dots (packed fp32) + DPP reduction (lane 63 valid) -------
        float gsum[4];
#pragma unroll
        for (int s = 0; s < 4; ++s) {
            float2 a2 = make_float2(0.f, 0.f);
#pragma unroll
            for (int i = 0; i < 8; ++i) {
                a2.x = fmaf(wreg2[s][i].x, hval2[i].x, a2.x);
                a2.y = fmaf(wreg2[s][i].y, hval2[i].y, a2.y);
            }
            gsum[s] = dpp_reduce_add(a2.x + a2.y);
        }

        // Activations — only lane 63's values are meaningful.
        float ig = sigm_f(xv[0] + gsum[0]);
        float fg = sigm_f(xv[1] + gsum[1]);
        float gv = tanh_f(xv[2] + gsum[2]);
        float og = sigm_f(xv[3] + gsum[3]);
        c = fg * c + ig * gv;
        float h = og * tanh_f(c);

        // ---- hand off to the gatherer via LDS (no barrier) -----------------
        if (l == 63) {
            hout_h[w] = h;
            __hip_atomic_store(&hout_tag[w], (uint32_t)(t + 1),
                               __ATOMIC_RELEASE, __HIP_MEMORY_SCOPE_WORKGROUP);
        }

        // ---- wave 4 (non-polling): spin-gather + single-line publish -------
        if (w == 4) {
            const uint32_t want = (uint32_t)(t + 1);
            for (;;) {
                uint32_t tg = (l < NW)
                    ? __hip_atomic_load(&hout_tag[l], __ATOMIC_ACQUIRE,
                                        __HIP_MEMORY_SCOPE_WORKGROUP)
                    : want;
                if (__all(tg == want)) break;
            }
            if (l < NW) {
                float hv = hout_h[l];
                u64 pub = ((u64)want << 32) | (u64)__float_as_uint(hv);
                __hip_atomic_store(&hdata[((size_t)buf << 10) + b * NW + l], pub,
                                   __ATOMIC_RELAXED, __HIP_MEMORY_SCOPE_AGENT);
                hs[(size_t)(t + 1) * HID + b * NW + l] = hv;   // epilogue copy
            }
        }

#pragma unroll
        for (int s = 0; s < 4; ++s) xv[s] = xn[s];
    }
}

// ---------------------------------------------------------------------------
// Kernel 3: logits = hs @ W_lin^T + b_lin ; softmax over O=2.
// ---------------------------------------------------------------------------
__global__ __launch_bounds__(256) void proj_softmax(
    const float* __restrict__ hs,    // [(T+1)][1024], rows 1..T are h_t
    const float* __restrict__ Wl,    // [2][1024]
    const float* __restrict__ bl,    // [2]
    float* __restrict__ out)         // [T][2]
{
    const int tid = threadIdx.x;
    const int w = tid >> 6, l = tid & 63;
    const int row = blockIdx.x * 4 + w;            // 0..8191
    const float* h = &hs[(size_t)(row + 1) * HID];

    float a0 = 0.f, a1 = 0.f;
#pragma unroll
    for (int i = 0; i < 4; ++i) {
        float4 hv = *(const float4*)&h[256 * i + 4 * l];
        float4 w0 = *(const float4*)&Wl[256 * i + 4 * l];
        float4 w1 = *(const float4*)&Wl[HID + 256 * i + 4 * l];
        a0 = fmaf(hv.x, w0.x, a0); a0 = fmaf(hv.y, w0.y, a0);
        a0 = fmaf(hv.z, w0.z, a0); a0 = fmaf(hv.w, w0.w, a0);
        a1 = fmaf(hv.x, w1.x, a1); a1 = fmaf(hv.y, w1.y, a1);
        a1 = fmaf(hv.z, w1.z, a1); a1 = fmaf(hv.w, w1.w, a1);
    }
#pragma unroll
    for (int off = 1; off < 64; off <<= 1) {
        a0 += __shfl_xor(a0, off, 64);
        a1 += __shfl_xor(a1, off, 64);
    }
    if (l == 0) {
        float l0 = a0 + bl[0];
        float l1 = a1 + bl[1];
        float m  = fmaxf(l0, l1);
        float e0 = __expf(l0 - m), e1 = __expf(l1 - m);
        float inv = 1.f / (e0 + e1);
        float2 o = make_float2(e0 * inv, e1 * inv);
        *(float2*)&out[(size_t)row * 2] = o;
    }
}

// ---------------------------------------------------------------------------
extern "C" void kernel_launch(void* const* d_in, const int* in_sizes, int n_in,
                              void* d_out, int out_size, void* d_ws, size_t ws_size,
                              hipStream_t stream)
{
    const float* input = (const float*)d_in[0];   // [8192][512]
    const float* W_ih  = (const float*)d_in[1];   // [4096][512]
    const float* W_hh  = (const float*)d_in[2];   // [4096][1024]
    const float* b_ih  = (const float*)d_in[3];   // [4096]
    const float* b_hh  = (const float*)d_in[4];   // [4096]
    const float* W_lin = (const float*)d_in[5];   // [2][1024]
    const float* b_lin = (const float*)d_in[6];   // [2]
    float* out = (float*)d_out;                   // [8192][2]

    char* ws = (char*)d_ws;
    float* hs     = (float*)ws;                          // (T+1)*1024 f32
    size_t hs_b   = (size_t)(T_STEPS + 1) * HID * sizeof(float);
    u64*   hdata  = (u64*)(ws + hs_b);                   // 2*1024 u64
    size_t hd_b   = 2 * 1024 * sizeof(u64);
    float* xg     = (float*)(ws + hs_b + hd_b);          // T*4096 f32

    // No memsets needed: 0xAA poison (0xAAAAAAAA) never equals a valid tag
    // (1..8192), hs row 0 is never read, and t=0 uses in-register zeros.

    dim3 g1(G4 / 128, T_STEPS / 128);
    gemm_xgates<<<g1, 256, 0, stream>>>(input, W_ih, b_ih, b_hh, xg);

    lstm_rec<<<NBLK, NW * 64, 0, stream>>>(W_hh, xg, hs, hdata);

    proj_softmax<<<T_STEPS / 4, 256, 0, stream>>>(hs, W_lin, b_lin, out);
}